// Round 9
// baseline (176.395 us; speedup 1.0000x reference)
//
#include <hip/hip_runtime.h>
#include <math.h>

#define S_LEN 2048
#define DMODEL 512
#define HDIM 64
#define EPS_G 1e-8f

typedef __bf16 bf16x8 __attribute__((ext_vector_type(8)));
typedef __bf16 bf16x4 __attribute__((ext_vector_type(4)));
typedef float f32x4 __attribute__((ext_vector_type(4)));

// DPP lane move within 16-lane rows; OOB lanes keep `oldv` (bound_ctrl=false).
template <int CTRL>
__device__ __forceinline__ float dpp_mov(float src, float oldv) {
  return __int_as_float(__builtin_amdgcn_update_dpp(
      __float_as_int(oldv), __float_as_int(src), CTRL, 0xF, 0xF, false));
}
#define ROW_SHL(n) (0x100 + (n))
#define ROW_SHR(n) (0x110 + (n))

__device__ __forceinline__ float swz_head(float v) {  // lane -> row head
  return __int_as_float(__builtin_amdgcn_ds_swizzle(__float_as_int(v), 0x0010));
}
__device__ __forceinline__ float swz_tail(float v) {  // lane -> row tail
  return __int_as_float(__builtin_amdgcn_ds_swizzle(__float_as_int(v), 0x01F0));
}

// ---------------------------------------------------------------------------
// Kernel 0: one-shot f32->bf16 conversion of X, Wq|Wk|Wv (stacked), Wo.
// ---------------------------------------------------------------------------
__global__ __launch_bounds__(256) void cvt_kernel(
    const float* __restrict__ X, const float* __restrict__ Wq,
    const float* __restrict__ Wk, const float* __restrict__ Wv,
    const float* __restrict__ Wo,
    __bf16* __restrict__ Xb, __bf16* __restrict__ Wb, __bf16* __restrict__ Wob) {
  const int u = blockIdx.x * 256 + threadIdx.x;   // float4 unit, 786432 total
  const float* src; __bf16* dst; int off;
  if (u < 524288)      { src = X;  dst = Xb;          off = u; }
  else if (u < 589824) { src = Wq; dst = Wb;          off = u - 524288; }
  else if (u < 655360) { src = Wk; dst = Wb + 262144; off = u - 589824; }
  else if (u < 720896) { src = Wv; dst = Wb + 524288; off = u - 655360; }
  else                 { src = Wo; dst = Wob;         off = u - 720896; }
  const float4 v = *(const float4*)(src + (size_t)off * 4);
  bf16x4 o;
  o[0] = (__bf16)v.x; o[1] = (__bf16)v.y; o[2] = (__bf16)v.z; o[3] = (__bf16)v.w;
  *(bf16x4*)(dst + (size_t)off * 4) = o;
}

// ---------------------------------------------------------------------------
// Kernel 1: fused QKV projection (bf16 MFMA, register-prefetch dbuf).
// R9 epilogue: native v_sin/v_cos (revolutions + fract reduction; libm
// sinf/cosf with ~2000-rad args hit the slow range-reduction path) and the
// trig is computed ONCE per (reg,nt) shared by Q and K (was 2x).  Single
// barrier phase: Q->Xs, K->Wls[0], V->Wls[1] bounces, then 3 stores.
// ---------------------------------------------------------------------------
__global__ __launch_bounds__(256, 2) void qkv_gemm(
    const __bf16* __restrict__ Xb, const __bf16* __restrict__ Wb,
    const float* __restrict__ bq, const float* __restrict__ bk, const float* __restrict__ bv,
    const int* __restrict__ pos,
    __bf16* __restrict__ Qh, __bf16* __restrict__ Kh, __bf16* __restrict__ Vt) {
  const int i0 = blockIdx.x << 6;
  const int h  = blockIdx.y;           // 0..7
  const int j0 = h << 6;

  __shared__ __bf16 Xs[64][72];
  __shared__ __bf16 Wls[3][64][72];

  const int tid = threadIdx.x;
  const int wv = tid >> 6, lane = tid & 63;
  const int l = lane & 15, seg = lane >> 4;
  const int sr = tid >> 2, sc = (tid & 3) << 4;

  f32x4 O[3][4];
#pragma unroll
  for (int w = 0; w < 3; ++w)
#pragma unroll
    for (int nt = 0; nt < 4; ++nt) O[w][nt] = (f32x4){0.f, 0.f, 0.f, 0.f};

  bf16x8 xr0, xr1, wr[3][2];
#define LOADQKV(K0)                                                                   \
  {                                                                                   \
    const __bf16* xp = Xb + (size_t)(i0 + sr) * 512 + (K0) + sc;                      \
    xr0 = *(const bf16x8*)xp; xr1 = *(const bf16x8*)(xp + 8);                         \
    _Pragma("unroll")                                                                 \
    for (int w = 0; w < 3; ++w) {                                                     \
      const __bf16* wp = Wb + (size_t)w * 262144 + (size_t)(j0 + sr) * 512 + (K0) + sc;\
      wr[w][0] = *(const bf16x8*)wp; wr[w][1] = *(const bf16x8*)(wp + 8);             \
    }                                                                                 \
  }

  LOADQKV(0)
  for (int k0 = 0; k0 < 512; k0 += 64) {
    __syncthreads();
    *(bf16x8*)&Xs[sr][sc]     = xr0;
    *(bf16x8*)&Xs[sr][sc + 8] = xr1;
#pragma unroll
    for (int w = 0; w < 3; ++w) {
      *(bf16x8*)&Wls[w][sr][sc]     = wr[w][0];
      *(bf16x8*)&Wls[w][sr][sc + 8] = wr[w][1];
    }
    __syncthreads();
    if (k0 < 448) LOADQKV(k0 + 64)

    bf16x8 a0 = *(const bf16x8*)&Xs[wv * 16 + l][seg * 8];
    bf16x8 a1 = *(const bf16x8*)&Xs[wv * 16 + l][seg * 8 + 32];
#pragma unroll
    for (int w = 0; w < 3; ++w)
#pragma unroll
      for (int nt = 0; nt < 4; ++nt) {
        bf16x8 b0 = *(const bf16x8*)&Wls[w][nt * 16 + l][seg * 8];
        bf16x8 b1 = *(const bf16x8*)&Wls[w][nt * 16 + l][seg * 8 + 32];
        O[w][nt] = __builtin_amdgcn_mfma_f32_16x16x32_bf16(a0, b0, O[w][nt], 0, 0, 0);
        O[w][nt] = __builtin_amdgcn_mfma_f32_16x16x32_bf16(a1, b1, O[w][nt], 0, 0, 0);
      }
  }

  const float* const bsrc[3] = {bq, bk, bv};
#pragma unroll
  for (int w = 0; w < 3; ++w)
#pragma unroll
    for (int nt = 0; nt < 4; ++nt) {
      const float bb = bsrc[w][j0 + nt * 16 + l];
#pragma unroll
      for (int reg = 0; reg < 4; ++reg) O[w][nt][reg] += bb;
    }

  const int n = i0 >> 11, sb = i0 & 2047;
  const int nh = (n << 3) + h;
  const int sl = wv * 16 + seg * 4;    // +reg

  float invf[4], l2sv[4];              // invf in REVOLUTIONS per unit pos
#pragma unroll
  for (int nt = 0; nt < 4; ++nt) {
    const float kp = (float)((nt * 16 + l) >> 1);
    invf[nt] = exp2f(-0.41524100f * kp) * 0.15915494f;
    l2sv[nt] = log2f((2.f * kp + 25.6f) * (1.f / 89.6f));
  }
  float pv_[4];
#pragma unroll
  for (int reg = 0; reg < 4; ++reg)
    pv_[reg] = (float)pos[n * S_LEN + sb + sl + reg];

  __syncthreads();   // last MFMA reads done; Xs/Wls become epilogue bounces

#pragma unroll
  for (int reg = 0; reg < 4; ++reg) {
    const float p = pv_[reg];
#pragma unroll
    for (int nt = 0; nt < 4; ++nt) {
      const int d = nt * 16 + l;
      const float rev0 = p * invf[nt];
      const float rev  = rev0 - floorf(rev0);
      const float sn = __builtin_amdgcn_sinf(rev);
      const float cn = __builtin_amdgcn_cosf(rev);
      const float e  = p * (1.f / 512.f) * l2sv[nt];
      const float sq = exp2f(e);
      const float sQ = sq * 0.125f;                      // fused HEAD_DIM^-0.5
      const float sK = __builtin_amdgcn_rcpf(sq);        // downscale for K
      float x  = O[0][nt][reg];
      float xp = __shfl_xor(x, 1);
      Xs[sl + reg][d] =
          (__bf16)((((d & 1) ? (x * cn + xp * sn) : (x * cn - xp * sn))) * sQ);
      x  = O[1][nt][reg];
      xp = __shfl_xor(x, 1);
      Wls[0][sl + reg][d] =
          (__bf16)((((d & 1) ? (x * cn + xp * sn) : (x * cn - xp * sn))) * sK);
      Wls[1][sl + reg][d] = (__bf16)O[2][nt][reg];
    }
  }
  __syncthreads();

  __bf16* qdst = Qh + (((size_t)nh * S_LEN + sb + sr) << 6) + sc;
  *(bf16x8*)qdst       = *(bf16x8*)&Xs[sr][sc];
  *(bf16x8*)(qdst + 8) = *(bf16x8*)&Xs[sr][sc + 8];
  __bf16* kdst = Kh + (((size_t)nh * S_LEN + sb + sr) << 6) + sc;
  *(bf16x8*)kdst       = *(bf16x8*)&Wls[0][sr][sc];
  *(bf16x8*)(kdst + 8) = *(bf16x8*)&Wls[0][sr][sc + 8];

  const int d = tid >> 2, part = tid & 3;
  __bf16 tmp[16];
#pragma unroll
  for (int i = 0; i < 16; ++i) tmp[i] = Wls[1][part * 16 + i][d];
  __bf16* vdst = Vt + (((size_t)(nh * 64 + d)) << 11) + sb + part * 16;
  *(bf16x8*)vdst       = *(bf16x8*)&tmp[0];
  *(bf16x8*)(vdst + 8) = *(bf16x8*)&tmp[8];
}

// ---------------------------------------------------------------------------
// Kernel 2: sigmoid-gated attention, split-K chunks over 128-ROW Q blocks
// (R9).  8 waves/block (512 thr), 640 blocks: each K/V tile serves 128 rows
// (per-head tiles 528->272, staging ~halved), scheduling rounds 2.5->1.25,
// 4 waves/SIMD overlap the per-tile dependency chain.  Chunk algebra is
// R8's verified scheme: self-contained low-boundary via direct Q.K[m-1]
// dot; exports partial O + per-row product P; t=0 term exported as a0.
// ---------------------------------------------------------------------------
__global__ __launch_bounds__(512, 4) void attn_chunk(
    const __bf16* __restrict__ Qh, const __bf16* __restrict__ Kh,
    const __bf16* __restrict__ Vt, const float* __restrict__ imask,
    __bf16* __restrict__ att, float* __restrict__ PartO,
    float* __restrict__ PartP, float* __restrict__ PartA0) {
  const int id = 639 - blockIdx.x;     // heavy (high-t, 8-tile) chunks first
  const int nh = id & 15;
  const int t  = id >> 4;              // 0..39 chunk id within head
  int rb2, c, nc;
  if (t < 4)       { rb2 = t; c = 0; nc = 1; }
  else if (t < 12) { int u = t - 4;  rb2 = 4  + (u >> 1); c = u & 1; nc = 2; }
  else if (t < 24) { int u = t - 12; rb2 = 8  + u / 3;    c = u - 3 * (u / 3); nc = 3; }
  else             { int u = t - 24; rb2 = 12 + (u >> 2); c = u & 3; nc = 4; }
  const int hi = 2 * rb2 + 1 - (c << 3);
  const int lo = (c == nc - 1) ? 0 : hi - 7;

  const int n = nh >> 3, h = nh & 7;
  const int tid = threadIdx.x;
  const int wv = tid >> 6, lane = tid & 63;
  const int l = lane & 15, seg = lane >> 4;
  const int pr = tid >> 3, pc = (tid & 7) << 3;   // 64x64 tile: 1 bf16x8/thread

  __shared__ __bf16 Qs16[128][72];
  __shared__ __bf16 Ks16[64][72];
  __shared__ __bf16 Vt16[64][72];
  __shared__ __bf16 cs16[128][72];
  __shared__ float msk[64];

  for (int idx = tid; idx < 1024; idx += 512) {
    int r = idx >> 3, c8 = (idx & 7) << 3;
    *(bf16x8*)&Qs16[r][c8] =
        *(const bf16x8*)(Qh + (((size_t)nh * S_LEN + rb2 * 128 + r) << 6) + c8);
  }

  f32x4 O[4];
  float pend[4][4];
  float Crow[4];
  float a0k0[4];
#pragma unroll
  for (int nt = 0; nt < 4; ++nt) O[nt] = (f32x4){0.f, 0.f, 0.f, 0.f};
#pragma unroll
  for (int r = 0; r < 4; ++r) {
    Crow[r] = 1.f; a0k0[r] = 0.f;
#pragma unroll
    for (int nt = 0; nt < 4; ++nt) pend[r][nt] = 0.f;
  }

  bf16x8 kp0, vp0;
  float mp = 0.f;
#define LOADKV(JT)                                                                  \
  kp0 = *(const bf16x8*)(Kh + (((size_t)nh * S_LEN + (JT) * 64 + pr) << 6) + pc);   \
  vp0 = *(const bf16x8*)(Vt + (((size_t)(nh * 64 + pr)) << 11) + (JT) * 64 + pc);   \
  if (tid < 64) mp = imask[n * S_LEN + (JT) * 64 + tid];

  LOADKV(hi)

  for (int jt = hi; jt >= lo; --jt) {
    __syncthreads();
    *(bf16x8*)&Ks16[pr][pc] = kp0;
    *(bf16x8*)&Vt16[pr][pc] = vp0;
    if (tid < 64) msk[tid] = mp;
    __syncthreads();
    if (jt > lo) { LOADKV(jt - 1) }

    // ---- QK^T MFMAs ----
    bf16x8 aq0 = *(const bf16x8*)&Qs16[wv * 16 + l][seg * 8];
    bf16x8 aq1 = *(const bf16x8*)&Qs16[wv * 16 + l][seg * 8 + 32];
    f32x4 Sv[4];
#pragma unroll
    for (int nt = 0; nt < 4; ++nt) {
      bf16x8 bk0 = *(const bf16x8*)&Ks16[nt * 16 + l][seg * 8];
      bf16x8 bk1 = *(const bf16x8*)&Ks16[nt * 16 + l][seg * 8 + 32];
      f32x4 z = (f32x4){0.f, 0.f, 0.f, 0.f};
      z = __builtin_amdgcn_mfma_f32_16x16x32_bf16(aq0, bk0, z, 0, 0, 0);
      z = __builtin_amdgcn_mfma_f32_16x16x32_bf16(aq1, bk1, z, 0, 0, 0);
      Sv[nt] = z;
    }

    float v0f[4];
#pragma unroll
    for (int nt = 0; nt < 4; ++nt) v0f[nt] = (float)Vt16[nt * 16 + l][0];

    // ---- gate scan + coefficients, per query row ----
#pragma unroll
    for (int reg = 0; reg < 4; ++reg) {
      const int qrow = rb2 * 128 + wv * 16 + seg * 4 + reg;
      float a_[4], f_[4], p_[4];
#pragma unroll
      for (int nt = 0; nt < 4; ++nt) {
        const int key = jt * 64 + nt * 16 + l;
        const float s = Sv[nt][reg];
        const float mv = msk[nt * 16 + l];
        const float av = (key <= qrow)
            ? mv * __builtin_amdgcn_rcpf(1.f + __expf(-s))
            : 0.f;
        a_[nt] = av;
        f_[nt] = 1.f - av + EPS_G;
      }
#pragma unroll
      for (int nt = 0; nt < 4; ++nt) {
        float p = f_[nt];
        p *= dpp_mov<ROW_SHL(1)>(p, 1.f);
        p *= dpp_mov<ROW_SHL(2)>(p, 1.f);
        p *= dpp_mov<ROW_SHL(4)>(p, 1.f);
        p *= dpp_mov<ROW_SHL(8)>(p, 1.f);
        p_[nt] = p;
      }
      float P_[4], tl[4];
#pragma unroll
      for (int nt = 0; nt < 4; ++nt) {
        P_[nt] = swz_head(p_[nt]);
        tl[nt] = swz_tail(f_[nt]);
      }
      const float a0 = swz_head(a_[0]);
      const float T3 = 1.f, T2 = P_[3], T1 = T2 * P_[2], T0 = T1 * P_[1];
      const float Tarr[4] = {T0, T1, T2, T3};
      const float Ptile = T0 * P_[0];
      const float crow = Crow[reg];
#pragma unroll
      for (int nt = 0; nt < 4; ++nt) {
        const float pprev = dpp_mov<ROW_SHR(1)>(p_[nt], 0.f);
        float cv;
        if (l > 0)
          cv = a_[nt] * pprev * Tarr[nt] * crow;
        else if (nt > 0)
          cv = a_[nt] * tl[nt - 1] * P_[nt] * Tarr[nt] * crow;
        else
          cv = (jt == 0 && nc == 1) ? a_[0] : 0.f;  // t=0 direct only if unsplit
        cs16[wv * 16 + seg * 4 + reg][nt * 16 + l] = (__bf16)cv;
      }
      if (jt == 0) a0k0[reg] = a0;
      const float f63 = tl[3];
      const float s0  = a0 * Ptile * crow;
      Crow[reg] = crow * Ptile;
#pragma unroll
      for (int nt = 0; nt < 4; ++nt) {
        O[nt][reg] += pend[reg][nt] * f63;
        pend[reg][nt] = s0 * v0f[nt];
      }
    }

    // ---- PV MFMAs ----
    bf16x8 ac0 = *(const bf16x8*)&cs16[wv * 16 + l][seg * 8];
    bf16x8 ac1 = *(const bf16x8*)&cs16[wv * 16 + l][seg * 8 + 32];
#pragma unroll
    for (int nt = 0; nt < 4; ++nt) {
      bf16x8 bv0 = *(const bf16x8*)&Vt16[nt * 16 + l][seg * 8];
      bf16x8 bv1 = *(const bf16x8*)&Vt16[nt * 16 + l][seg * 8 + 32];
      O[nt] = __builtin_amdgcn_mfma_f32_16x16x32_bf16(ac0, bv0, O[nt], 0, 0, 0);
      O[nt] = __builtin_amdgcn_mfma_f32_16x16x32_bf16(ac1, bv1, O[nt], 0, 0, 0);
    }
  }

  // ---- low-boundary pending resolution (chunk does not reach key 0) ----
  if (lo > 0) {
    const int m = lo << 6;
    const float mb = imask[n * S_LEN + m - 1];
    const __bf16* kb = Kh + (((size_t)nh * S_LEN + m - 1) << 6) + seg * 16;
    bf16x8 kb0 = *(const bf16x8*)kb, kb1 = *(const bf16x8*)(kb + 8);
    bf16x8 q0 = *(const bf16x8*)&Qs16[wv * 16 + l][seg * 16];
    bf16x8 q1 = *(const bf16x8*)&Qs16[wv * 16 + l][seg * 16 + 8];
    float sc_ = 0.f;
#pragma unroll
    for (int j = 0; j < 8; ++j)
      sc_ += (float)q0[j] * (float)kb0[j] + (float)q1[j] * (float)kb1[j];
    sc_ += __shfl_xor(sc_, 16);
    sc_ += __shfl_xor(sc_, 32);
    const float fbl = 1.f - mb * __builtin_amdgcn_rcpf(1.f + __expf(-sc_)) + EPS_G;
#pragma unroll
    for (int reg = 0; reg < 4; ++reg) {
      const float fb = __shfl(fbl, (seg << 2) + reg);   // lane l = seg*4+reg
#pragma unroll
      for (int nt = 0; nt < 4; ++nt) O[nt][reg] += pend[reg][nt] * fb;
    }
  }

  if (nc == 1) {
#pragma unroll
    for (int nt = 0; nt < 4; ++nt)
#pragma unroll
      for (int reg = 0; reg < 4; ++reg) {
        const int srow = rb2 * 128 + wv * 16 + seg * 4 + reg;
        att[((size_t)(n * S_LEN + srow)) * DMODEL + h * HDIM + nt * 16 + l] =
            (__bf16)O[nt][reg];
      }
  } else {
    const int slot = nh * 36 + (t - 4);
    float* po = PartO + (size_t)slot * 8192;
#pragma unroll
    for (int nt = 0; nt < 4; ++nt)
#pragma unroll
      for (int reg = 0; reg < 4; ++reg)
        po[(wv * 16 + seg * 4 + reg) * 64 + nt * 16 + l] = O[nt][reg];
    if (l == 0) {
#pragma unroll
      for (int reg = 0; reg < 4; ++reg)
        PartP[slot * 128 + wv * 16 + seg * 4 + reg] = Crow[reg];
      if (lo == 0) {
#pragma unroll
        for (int reg = 0; reg < 4; ++reg)
          PartA0[(nh * 12 + rb2 - 4) * 128 + wv * 16 + seg * 4 + reg] = a0k0[reg];
      }
    }
  }
}

// ---------------------------------------------------------------------------
// Kernel 3: combine chunk partials: O = sum_c (prod_{c'<c} P_c') O_c + a0 (x) V0
// One block per (nh, rb2>=4) = 192 blocks; 128 rows x 64 dims each.
// ---------------------------------------------------------------------------
__global__ __launch_bounds__(256) void combine_kernel(
    const float* __restrict__ PartO, const float* __restrict__ PartP,
    const float* __restrict__ PartA0, const __bf16* __restrict__ Vt,
    __bf16* __restrict__ att) {
  const int b = blockIdx.x;            // 16 x 12
  const int nh = b / 12;
  const int rb2 = 4 + (b - nh * 12);
  const int nc = (rb2 < 8) ? 2 : ((rb2 < 12) ? 3 : 4);
  const int t0 = (rb2 < 8) ? 4 + ((rb2 - 4) << 1)
               : (rb2 < 12) ? 12 + (rb2 - 8) * 3
                            : 24 + ((rb2 - 12) << 2);
  const int n = nh >> 3, h = nh & 7;
  const int tid = threadIdx.x;
  const int r = tid >> 1, db = (tid & 1) << 5;   // row 0..127, dim half 0/32

  float acc[32];
#pragma unroll
  for (int j = 0; j < 32; ++j) acc[j] = 0.f;
  float fac = 1.f;
  for (int c = 0; c < nc; ++c) {
    const int slot = nh * 36 + (t0 - 4) + c;
    const float* po = PartO + (size_t)slot * 8192 + r * 64 + db;
    const float P = PartP[slot * 128 + r];
#pragma unroll
    for (int q = 0; q < 8; ++q) {
      const float4 v = *(const float4*)(po + q * 4);
      acc[q * 4 + 0] += fac * v.x; acc[q * 4 + 1] += fac * v.y;
      acc[q * 4 + 2] += fac * v.z; acc[q * 4 + 3] += fac * v.w;
    }
    fac *= P;
  }
  const float a0 = PartA0[(nh * 12 + rb2 - 4) * 128 + r];
#pragma unroll
  for (int j = 0; j < 32; ++j)
    acc[j] += a0 * (float)Vt[(((size_t)(nh * 64 + db + j)) << 11)];

  __bf16 ob[32];
#pragma unroll
  for (int j = 0; j < 32; ++j) ob[j] = (__bf16)acc[j];
  __bf16* dst = att + ((size_t)(n * S_LEN + rb2 * 128 + r)) * DMODEL + h * HDIM + db;
  *(bf16x8*)dst        = *(bf16x8*)&ob[0];
  *(bf16x8*)(dst + 8)  = *(bf16x8*)&ob[8];
  *(bf16x8*)(dst + 16) = *(bf16x8*)&ob[16];
  *(bf16x8*)(dst + 24) = *(bf16x8*)&ob[24];
}

// ---------------------------------------------------------------------------
// Kernel 4: out = att @ Wo^T + bo.  64x128 tile, bf16 staging, register-
// prefetch double-buffered K-loop.
// ---------------------------------------------------------------------------
__global__ __launch_bounds__(256, 2) void out_gemm(const __bf16* __restrict__ Xa,
                                                   const __bf16* __restrict__ Wob,
                                                   const float* __restrict__ bo,
                                                   float* __restrict__ Out) {
  const int i0 = blockIdx.x << 6, j0 = blockIdx.y << 7;
  __shared__ __bf16 As[64][72];
  __shared__ __bf16 Bs[128][72];

  const int tid = threadIdx.x;
  const int wv = tid >> 6, lane = tid & 63;
  const int l = lane & 15, seg = lane >> 4;
  const int sr = tid >> 2, sc = (tid & 3) << 4;

  f32x4 O[8];
#pragma unroll
  for (int nt = 0; nt < 8; ++nt) O[nt] = (f32x4){0.f, 0.f, 0.f, 0.f};

  bf16x8 ar0, ar1, br[2][2];
#define LOADOUT(K0)                                                          \
  {                                                                          \
    const __bf16* xp = Xa + (size_t)(i0 + sr) * 512 + (K0) + sc;             \
    ar0 = *(const bf16x8*)xp; ar1 = *(const bf16x8*)(xp + 8);                \
    _Pragma("unroll")                                                        \
    for (int ps = 0; ps < 2; ++ps) {                                         \
      const __bf16* wp = Wob + (size_t)(j0 + ps * 64 + sr) * 512 + (K0) + sc;\
      br[ps][0] = *(const bf16x8*)wp; br[ps][1] = *(const bf16x8*)(wp + 8);  \
    }                                                                        \
  }

  LOADOUT(0)
  for (int k0 = 0; k0 < 512; k0 += 64) {
    __syncthreads();
    *(bf16x8*)&As[sr][sc]     = ar0;
    *(bf16x8*)&As[sr][sc + 8] = ar1;
#pragma unroll
    for (int ps = 0; ps < 2; ++ps) {
      *(bf16x8*)&Bs[ps * 64 + sr][sc]     = br[ps][0];
      *(bf16x8*)&Bs[ps * 64 + sr][sc + 8] = br[ps][1];
    }
    __syncthreads();
    if (k0 < 448) LOADOUT(k0 + 64)

    bf16x8 a0 = *(const bf16x8*)&As[wv * 16 + l][seg * 8];
    bf16x8 a1 = *(const bf16x8*)&As[wv * 16 + l][seg * 8 + 32];
#pragma unroll
    for (int nt = 0; nt < 8; ++nt) {
      bf16x8 b0 = *(const bf16x8*)&Bs[nt * 16 + l][seg * 8];
      bf16x8 b1 = *(const bf16x8*)&Bs[nt * 16 + l][seg * 8 + 32];
      O[nt] = __builtin_amdgcn_mfma_f32_16x16x32_bf16(a0, b0, O[nt], 0, 0, 0);
      O[nt] = __builtin_amdgcn_mfma_f32_16x16x32_bf16(a1, b1, O[nt], 0, 0, 0);
    }
  }

#pragma unroll
  for (int nt = 0; nt < 8; ++nt) {
    const float bb = bo[j0 + nt * 16 + l];
#pragma unroll
    for (int reg = 0; reg < 4; ++reg) {
      const int m = wv * 16 + seg * 4 + reg;
      Out[(size_t)(i0 + m) * 512 + j0 + nt * 16 + l] = O[nt][reg] + bb;
    }
  }
}

// ---------------------------------------------------------------------------
extern "C" void kernel_launch(void* const* d_in, const int* in_sizes, int n_in,
                              void* d_out, int out_size, void* d_ws, size_t ws_size,
                              hipStream_t stream) {
  (void)in_sizes; (void)n_in; (void)out_size; (void)ws_size;
  const float* seq  = (const float*)d_in[0];
  const float* mask = (const float*)d_in[1];
  const int*   pos  = (const int*)d_in[2];
  const float* Wq = (const float*)d_in[4];
  const float* bq = (const float*)d_in[5];
  const float* Wk = (const float*)d_in[6];
  const float* bk = (const float*)d_in[7];
  const float* Wv = (const float*)d_in[8];
  const float* bv = (const float*)d_in[9];
  const float* Wo = (const float*)d_in[10];
  const float* bo = (const float*)d_in[11];
  float* out = (float*)d_out;

  char* base = (char*)d_ws;
  __bf16* att = (__bf16*)base;                     // 4 MB  (4096 x 512 bf16)
  __bf16* Qh  = (__bf16*)(base + ( 4u << 20));     // 4 MB
  __bf16* Kh  = (__bf16*)(base + ( 8u << 20));     // 4 MB
  __bf16* Vt  = (__bf16*)(base + (12u << 20));     // 4 MB  [nh][d][2048]
  __bf16* Wb  = (__bf16*)(base + (16u << 20));     // 1.5 MB
  __bf16* Wob = (__bf16*)(base + (18u << 20));     // 0.5 MB
  __bf16* Xb  = (__bf16*)(base + (19u << 20));     // 4 MB  (dead after qkv)
  float* PartO  = (float*)(base + (23u << 20));    // 16*36*8192*4 = 18.9 MB
  float* PartP  = (float*)(base + (42u << 20));    // 16*36*128*4  = 295 KB
  float* PartA0 = (float*)(base + (43u << 20));    // 16*12*128*4  = 98 KB

  cvt_kernel<<<3072, 256, 0, stream>>>(seq, Wq, Wk, Wv, Wo, Xb, Wb, Wob);
  qkv_gemm<<<dim3(64, 8), 256, 0, stream>>>(Xb, Wb, bq, bk, bv, pos, Qh, Kh, Vt);
  attn_chunk<<<640, 512, 0, stream>>>(Qh, Kh, Vt, mask, att, PartO, PartP, PartA0);
  combine_kernel<<<192, 256, 0, stream>>>(PartO, PartP, PartA0, Vt, att);
  out_gemm<<<dim3(64, 4), 256, 0, stream>>>(att, Wob, bo, out);
}

// Round 10
// 167.144 us; speedup vs baseline: 1.0553x; 1.0553x over previous
//
#include <hip/hip_runtime.h>
#include <math.h>

#define S_LEN 2048
#define DMODEL 512
#define HDIM 64
#define EPS_G 1e-8f

typedef __bf16 bf16x8 __attribute__((ext_vector_type(8)));
typedef __bf16 bf16x4 __attribute__((ext_vector_type(4)));
typedef float f32x4 __attribute__((ext_vector_type(4)));

// DPP lane move within 16-lane rows; OOB lanes keep `oldv` (bound_ctrl=false).
template <int CTRL>
__device__ __forceinline__ float dpp_mov(float src, float oldv) {
  return __int_as_float(__builtin_amdgcn_update_dpp(
      __float_as_int(oldv), __float_as_int(src), CTRL, 0xF, 0xF, false));
}
#define ROW_SHL(n) (0x100 + (n))
#define ROW_SHR(n) (0x110 + (n))

__device__ __forceinline__ float swz_head(float v) {  // lane -> row head
  return __int_as_float(__builtin_amdgcn_ds_swizzle(__float_as_int(v), 0x0010));
}
__device__ __forceinline__ float swz_tail(float v) {  // lane -> row tail
  return __int_as_float(__builtin_amdgcn_ds_swizzle(__float_as_int(v), 0x01F0));
}

// ---------------------------------------------------------------------------
// Kernel 0: one-shot f32->bf16 conversion of X, Wq|Wk|Wv (stacked), Wo.
// ---------------------------------------------------------------------------
__global__ __launch_bounds__(256) void cvt_kernel(
    const float* __restrict__ X, const float* __restrict__ Wq,
    const float* __restrict__ Wk, const float* __restrict__ Wv,
    const float* __restrict__ Wo,
    __bf16* __restrict__ Xb, __bf16* __restrict__ Wb, __bf16* __restrict__ Wob) {
  const int u = blockIdx.x * 256 + threadIdx.x;   // float4 unit, 786432 total
  const float* src; __bf16* dst; int off;
  if (u < 524288)      { src = X;  dst = Xb;          off = u; }
  else if (u < 589824) { src = Wq; dst = Wb;          off = u - 524288; }
  else if (u < 655360) { src = Wk; dst = Wb + 262144; off = u - 589824; }
  else if (u < 720896) { src = Wv; dst = Wb + 524288; off = u - 655360; }
  else                 { src = Wo; dst = Wob;         off = u - 720896; }
  const float4 v = *(const float4*)(src + (size_t)off * 4);
  bf16x4 o;
  o[0] = (__bf16)v.x; o[1] = (__bf16)v.y; o[2] = (__bf16)v.z; o[3] = (__bf16)v.w;
  *(bf16x4*)(dst + (size_t)off * 4) = o;
}

// ---------------------------------------------------------------------------
// Kernel 1: fused QKV projection.  R10 wave decomposition: each wave owns
// ALL 64 rows (4 A-frags) x col-unit nt==wv x all 3 W matrices.
// Per k-iter per wave: 8 A-reads + 6 B-reads -> 24 MFMAs (ratio 1.7:1 vs
// R9's 0.96:1 — R5-R9's stuck ~110us non-attn time is the GEMMs' 1:1
// MFMA:ds_read_b128 ratio saturating the LDS pipe).
// Epilogue (nt=wv fixed): one trig set per (r4,reg); Q->Xs, K->Wls[0],
// V->Wls[1] bounces, coalesced stores; V transposed [nh][d][s].
// ---------------------------------------------------------------------------
__global__ __launch_bounds__(256, 2) void qkv_gemm(
    const __bf16* __restrict__ Xb, const __bf16* __restrict__ Wb,
    const float* __restrict__ bq, const float* __restrict__ bk, const float* __restrict__ bv,
    const int* __restrict__ pos,
    __bf16* __restrict__ Qh, __bf16* __restrict__ Kh, __bf16* __restrict__ Vt) {
  const int i0 = blockIdx.x << 6;
  const int h  = blockIdx.y;           // 0..7
  const int j0 = h << 6;

  __shared__ __bf16 Xs[64][72];
  __shared__ __bf16 Wls[3][64][72];

  const int tid = threadIdx.x;
  const int wv = tid >> 6, lane = tid & 63;
  const int l = lane & 15, seg = lane >> 4;
  const int sr = tid >> 2, sc = (tid & 3) << 4;

  f32x4 O[3][4];                       // [w][r4], rows r4*16+seg*4+reg, col wv*16+l
#pragma unroll
  for (int w = 0; w < 3; ++w)
#pragma unroll
    for (int r4 = 0; r4 < 4; ++r4) O[w][r4] = (f32x4){0.f, 0.f, 0.f, 0.f};

  bf16x8 xr0, xr1, wr[3][2];
#define LOADQKV(K0)                                                                   \
  {                                                                                   \
    const __bf16* xp = Xb + (size_t)(i0 + sr) * 512 + (K0) + sc;                      \
    xr0 = *(const bf16x8*)xp; xr1 = *(const bf16x8*)(xp + 8);                         \
    _Pragma("unroll")                                                                 \
    for (int w = 0; w < 3; ++w) {                                                     \
      const __bf16* wp = Wb + (size_t)w * 262144 + (size_t)(j0 + sr) * 512 + (K0) + sc;\
      wr[w][0] = *(const bf16x8*)wp; wr[w][1] = *(const bf16x8*)(wp + 8);             \
    }                                                                                 \
  }

  LOADQKV(0)
  for (int k0 = 0; k0 < 512; k0 += 64) {
    __syncthreads();
    *(bf16x8*)&Xs[sr][sc]     = xr0;
    *(bf16x8*)&Xs[sr][sc + 8] = xr1;
#pragma unroll
    for (int w = 0; w < 3; ++w) {
      *(bf16x8*)&Wls[w][sr][sc]     = wr[w][0];
      *(bf16x8*)&Wls[w][sr][sc + 8] = wr[w][1];
    }
    __syncthreads();
    if (k0 < 448) LOADQKV(k0 + 64)

    bf16x8 a0[4], a1[4];
#pragma unroll
    for (int r4 = 0; r4 < 4; ++r4) {
      a0[r4] = *(const bf16x8*)&Xs[r4 * 16 + l][seg * 8];
      a1[r4] = *(const bf16x8*)&Xs[r4 * 16 + l][seg * 8 + 32];
    }
#pragma unroll
    for (int w = 0; w < 3; ++w) {
      bf16x8 b0 = *(const bf16x8*)&Wls[w][wv * 16 + l][seg * 8];
      bf16x8 b1 = *(const bf16x8*)&Wls[w][wv * 16 + l][seg * 8 + 32];
#pragma unroll
      for (int r4 = 0; r4 < 4; ++r4) {
        O[w][r4] = __builtin_amdgcn_mfma_f32_16x16x32_bf16(a0[r4], b0, O[w][r4], 0, 0, 0);
        O[w][r4] = __builtin_amdgcn_mfma_f32_16x16x32_bf16(a1[r4], b1, O[w][r4], 0, 0, 0);
      }
    }
  }

  // bias (col d = wv*16+l fixed per thread)
  const int d = wv * 16 + l;
  const float bbq = bq[j0 + d], bbk = bk[j0 + d], bbv = bv[j0 + d];
#pragma unroll
  for (int r4 = 0; r4 < 4; ++r4)
#pragma unroll
    for (int reg = 0; reg < 4; ++reg) {
      O[0][r4][reg] += bbq; O[1][r4][reg] += bbk; O[2][r4][reg] += bbv;
    }

  const int n = i0 >> 11, sb = i0 & 2047;
  const int nh = (n << 3) + h;

  // xpos constants: single (kp) per thread since nt==wv
  const float kp   = (float)(d >> 1);
  const float invf = exp2f(-0.41524100f * kp) * 0.15915494f;  // rev / unit pos
  const float l2sv = log2f((2.f * kp + 25.6f) * (1.f / 89.6f));
  float pv_[4][4];
#pragma unroll
  for (int r4 = 0; r4 < 4; ++r4)
#pragma unroll
    for (int reg = 0; reg < 4; ++reg)
      pv_[r4][reg] = (float)pos[n * S_LEN + sb + r4 * 16 + (seg << 2) + reg];

  __syncthreads();   // last MFMA reads done; Xs/Wls become epilogue bounces

#pragma unroll
  for (int r4 = 0; r4 < 4; ++r4)
#pragma unroll
    for (int reg = 0; reg < 4; ++reg) {
      const int row = r4 * 16 + (seg << 2) + reg;
      const float p = pv_[r4][reg];
      const float rev0 = p * invf;
      const float rev  = rev0 - floorf(rev0);
      const float sn = __builtin_amdgcn_sinf(rev);
      const float cn = __builtin_amdgcn_cosf(rev);
      const float sq = exp2f(p * (1.f / 512.f) * l2sv);
      const float sQ = sq * 0.125f;                   // fused HEAD_DIM^-0.5
      const float sK = __builtin_amdgcn_rcpf(sq);     // downscale for K
      float x  = O[0][r4][reg];
      float xp = __shfl_xor(x, 1);
      Xs[row][d] = (__bf16)((((d & 1) ? (x * cn + xp * sn) : (x * cn - xp * sn))) * sQ);
      x  = O[1][r4][reg];
      xp = __shfl_xor(x, 1);
      Wls[0][row][d] = (__bf16)((((d & 1) ? (x * cn + xp * sn) : (x * cn - xp * sn))) * sK);
      Wls[1][row][d] = (__bf16)O[2][r4][reg];
    }
  __syncthreads();

  __bf16* qdst = Qh + (((size_t)nh * S_LEN + sb + sr) << 6) + sc;
  *(bf16x8*)qdst       = *(bf16x8*)&Xs[sr][sc];
  *(bf16x8*)(qdst + 8) = *(bf16x8*)&Xs[sr][sc + 8];
  __bf16* kdst = Kh + (((size_t)nh * S_LEN + sb + sr) << 6) + sc;
  *(bf16x8*)kdst       = *(bf16x8*)&Wls[0][sr][sc];
  *(bf16x8*)(kdst + 8) = *(bf16x8*)&Wls[0][sr][sc + 8];

  const int dv = tid >> 2, part = tid & 3;
  __bf16 tmp[16];
#pragma unroll
  for (int i = 0; i < 16; ++i) tmp[i] = Wls[1][part * 16 + i][dv];
  __bf16* vdst = Vt + (((size_t)(nh * 64 + dv)) << 11) + sb + part * 16;
  *(bf16x8*)vdst       = *(bf16x8*)&tmp[0];
  *(bf16x8*)(vdst + 8) = *(bf16x8*)&tmp[8];
}

// ---------------------------------------------------------------------------
// Kernel 2: sigmoid-gated attention, split-K chunks (R8's proven version —
// R9's 128-row variant regressed 62->66us, reverted).  64-row Q blocks,
// <=8-tile chunks, 1280 blocks; chunk self-contained via direct Q.K[m-1]
// boundary dot; exports partial O + per-row product P; t=0 term as a0.
// ---------------------------------------------------------------------------
__global__ __launch_bounds__(256, 2) void attn_chunk(
    const __bf16* __restrict__ Qh, const __bf16* __restrict__ Kh,
    const __bf16* __restrict__ Vt, const float* __restrict__ imask,
    __bf16* __restrict__ att, float* __restrict__ PartO,
    float* __restrict__ PartP, float* __restrict__ PartA0) {
  const int id = blockIdx.x;
  const int nh = id & 15;
  const int t  = id >> 4;              // 0..79 chunk id within head
  int rb, c, nc;
  if (t < 8)       { rb = t; c = 0; nc = 1; }
  else if (t < 24) { int u = t - 8;  rb = 8  + (u >> 1); c = u & 1;     nc = 2; }
  else if (t < 48) { int u = t - 24; rb = 16 + u / 3;    c = u - 3 * (u / 3); nc = 3; }
  else             { int u = t - 48; rb = 24 + (u >> 2); c = u & 3;     nc = 4; }
  const int hi = rb - (c << 3);
  const int lo = (c == nc - 1) ? 0 : hi - 7;

  const int n = nh >> 3, h = nh & 7;
  const int tid = threadIdx.x;
  const int wv = tid >> 6, lane = tid & 63;
  const int l = lane & 15, seg = lane >> 4;
  const int pr = tid >> 3, pc = (tid & 7) << 3;

  __shared__ __bf16 Qs16[64][72];
  __shared__ __bf16 Ks16[64][72];
  __shared__ __bf16 Vt16[64][72];
  __shared__ __bf16 cs16[64][72];
  __shared__ float msk[64];

  for (int idx = tid; idx < 512; idx += 256) {
    int r = idx >> 3, c8 = (idx & 7) << 3;
    *(bf16x8*)&Qs16[r][c8] =
        *(const bf16x8*)(Qh + (((size_t)nh * S_LEN + rb * 64 + r) << 6) + c8);
  }

  f32x4 O[4];
  float pend[4][4];
  float Crow[4];
  float a0k0[4];
#pragma unroll
  for (int nt = 0; nt < 4; ++nt) O[nt] = (f32x4){0.f, 0.f, 0.f, 0.f};
#pragma unroll
  for (int r = 0; r < 4; ++r) {
    Crow[r] = 1.f; a0k0[r] = 0.f;
#pragma unroll
    for (int nt = 0; nt < 4; ++nt) pend[r][nt] = 0.f;
  }

  bf16x8 kp0, kp1, vp0, vp1;
  float mp = 0.f;
#define LOADKV(JT)                                                                     \
  kp0 = *(const bf16x8*)(Kh + (((size_t)nh * S_LEN + (JT) * 64 + pr) << 6) + pc);      \
  kp1 = *(const bf16x8*)(Kh + (((size_t)nh * S_LEN + (JT) * 64 + 32 + pr) << 6) + pc); \
  vp0 = *(const bf16x8*)(Vt + (((size_t)(nh * 64 + pr)) << 11) + (JT) * 64 + pc);      \
  vp1 = *(const bf16x8*)(Vt + (((size_t)(nh * 64 + 32 + pr)) << 11) + (JT) * 64 + pc); \
  if (tid < 64) mp = imask[n * S_LEN + (JT) * 64 + tid];

  LOADKV(hi)

  for (int jt = hi; jt >= lo; --jt) {
    __syncthreads();
    *(bf16x8*)&Ks16[pr][pc]      = kp0;
    *(bf16x8*)&Ks16[32 + pr][pc] = kp1;
    *(bf16x8*)&Vt16[pr][pc]      = vp0;
    *(bf16x8*)&Vt16[32 + pr][pc] = vp1;
    if (tid < 64) msk[tid] = mp;
    __syncthreads();
    if (jt > lo) { LOADKV(jt - 1) }

    // ---- QK^T MFMAs ----
    bf16x8 aq0 = *(const bf16x8*)&Qs16[wv * 16 + l][seg * 8];
    bf16x8 aq1 = *(const bf16x8*)&Qs16[wv * 16 + l][seg * 8 + 32];
    f32x4 Sv[4];
#pragma unroll
    for (int nt = 0; nt < 4; ++nt) {
      bf16x8 bk0 = *(const bf16x8*)&Ks16[nt * 16 + l][seg * 8];
      bf16x8 bk1 = *(const bf16x8*)&Ks16[nt * 16 + l][seg * 8 + 32];
      f32x4 z = (f32x4){0.f, 0.f, 0.f, 0.f};
      z = __builtin_amdgcn_mfma_f32_16x16x32_bf16(aq0, bk0, z, 0, 0, 0);
      z = __builtin_amdgcn_mfma_f32_16x16x32_bf16(aq1, bk1, z, 0, 0, 0);
      Sv[nt] = z;
    }

    float v0f[4];
#pragma unroll
    for (int nt = 0; nt < 4; ++nt) v0f[nt] = (float)Vt16[nt * 16 + l][0];

    // ---- gate scan + coefficients, per query row ----
#pragma unroll
    for (int reg = 0; reg < 4; ++reg) {
      const int qrow = rb * 64 + wv * 16 + seg * 4 + reg;
      float a_[4], f_[4], p_[4];
#pragma unroll
      for (int nt = 0; nt < 4; ++nt) {
        const int key = jt * 64 + nt * 16 + l;
        const float s = Sv[nt][reg];
        const float mv = msk[nt * 16 + l];
        const float av = (key <= qrow)
            ? mv * __builtin_amdgcn_rcpf(1.f + __expf(-s))
            : 0.f;
        a_[nt] = av;
        f_[nt] = 1.f - av + EPS_G;
      }
#pragma unroll
      for (int nt = 0; nt < 4; ++nt) {
        float p = f_[nt];
        p *= dpp_mov<ROW_SHL(1)>(p, 1.f);
        p *= dpp_mov<ROW_SHL(2)>(p, 1.f);
        p *= dpp_mov<ROW_SHL(4)>(p, 1.f);
        p *= dpp_mov<ROW_SHL(8)>(p, 1.f);
        p_[nt] = p;
      }
      float P_[4], tl[4];
#pragma unroll
      for (int nt = 0; nt < 4; ++nt) {
        P_[nt] = swz_head(p_[nt]);
        tl[nt] = swz_tail(f_[nt]);
      }
      const float a0 = swz_head(a_[0]);
      const float T3 = 1.f, T2 = P_[3], T1 = T2 * P_[2], T0 = T1 * P_[1];
      const float Tarr[4] = {T0, T1, T2, T3};
      const float Ptile = T0 * P_[0];
      const float crow = Crow[reg];
#pragma unroll
      for (int nt = 0; nt < 4; ++nt) {
        const float pprev = dpp_mov<ROW_SHR(1)>(p_[nt], 0.f);
        float cv;
        if (l > 0)
          cv = a_[nt] * pprev * Tarr[nt] * crow;
        else if (nt > 0)
          cv = a_[nt] * tl[nt - 1] * P_[nt] * Tarr[nt] * crow;
        else
          cv = (jt == 0 && nc == 1) ? a_[0] : 0.f;  // t=0 direct only if unsplit
        cs16[wv * 16 + seg * 4 + reg][nt * 16 + l] = (__bf16)cv;
      }
      if (jt == 0) a0k0[reg] = a0;
      const float f63 = tl[3];
      const float s0  = a0 * Ptile * crow;
      Crow[reg] = crow * Ptile;
#pragma unroll
      for (int nt = 0; nt < 4; ++nt) {
        O[nt][reg] += pend[reg][nt] * f63;
        pend[reg][nt] = s0 * v0f[nt];
      }
    }

    // ---- PV MFMAs ----
    bf16x8 ac0 = *(const bf16x8*)&cs16[wv * 16 + l][seg * 8];
    bf16x8 ac1 = *(const bf16x8*)&cs16[wv * 16 + l][seg * 8 + 32];
#pragma unroll
    for (int nt = 0; nt < 4; ++nt) {
      bf16x8 bv0 = *(const bf16x8*)&Vt16[nt * 16 + l][seg * 8];
      bf16x8 bv1 = *(const bf16x8*)&Vt16[nt * 16 + l][seg * 8 + 32];
      O[nt] = __builtin_amdgcn_mfma_f32_16x16x32_bf16(ac0, bv0, O[nt], 0, 0, 0);
      O[nt] = __builtin_amdgcn_mfma_f32_16x16x32_bf16(ac1, bv1, O[nt], 0, 0, 0);
    }
  }

  // ---- low-boundary pending resolution (chunk does not reach key 0) ----
  if (lo > 0) {
    const int m = lo << 6;
    const float mb = imask[n * S_LEN + m - 1];
    const __bf16* kb = Kh + (((size_t)nh * S_LEN + m - 1) << 6) + seg * 16;
    bf16x8 kb0 = *(const bf16x8*)kb, kb1 = *(const bf16x8*)(kb + 8);
    bf16x8 q0 = *(const bf16x8*)&Qs16[wv * 16 + l][seg * 16];
    bf16x8 q1 = *(const bf16x8*)&Qs16[wv * 16 + l][seg * 16 + 8];
    float sc_ = 0.f;
#pragma unroll
    for (int j = 0; j < 8; ++j)
      sc_ += (float)q0[j] * (float)kb0[j] + (float)q1[j] * (float)kb1[j];
    sc_ += __shfl_xor(sc_, 16);
    sc_ += __shfl_xor(sc_, 32);
    const float fbl = 1.f - mb * __builtin_amdgcn_rcpf(1.f + __expf(-sc_)) + EPS_G;
#pragma unroll
    for (int reg = 0; reg < 4; ++reg) {
      const float fb = __shfl(fbl, (seg << 2) + reg);   // lane l = seg*4+reg
#pragma unroll
      for (int nt = 0; nt < 4; ++nt) O[nt][reg] += pend[reg][nt] * fb;
    }
  }

  if (nc == 1) {
#pragma unroll
    for (int nt = 0; nt < 4; ++nt)
#pragma unroll
      for (int reg = 0; reg < 4; ++reg) {
        const int srow = rb * 64 + wv * 16 + seg * 4 + reg;
        att[((size_t)(n * S_LEN + srow)) * DMODEL + h * HDIM + nt * 16 + l] =
            (__bf16)O[nt][reg];
      }
  } else {
    const int slot = nh * 72 + (t - 8);
    float* po = PartO + (size_t)slot * 4096;
#pragma unroll
    for (int nt = 0; nt < 4; ++nt)
#pragma unroll
      for (int reg = 0; reg < 4; ++reg)
        po[(wv * 16 + seg * 4 + reg) * 64 + nt * 16 + l] = O[nt][reg];
    if (l == 0) {
#pragma unroll
      for (int reg = 0; reg < 4; ++reg)
        PartP[slot * 64 + wv * 16 + seg * 4 + reg] = Crow[reg];
      if (lo == 0) {
#pragma unroll
        for (int reg = 0; reg < 4; ++reg)
          PartA0[(nh * 24 + rb - 8) * 64 + wv * 16 + seg * 4 + reg] = a0k0[reg];
      }
    }
  }
}

// ---------------------------------------------------------------------------
// Kernel 3: combine chunk partials: O = sum_c (prod_{c'<c} P_c') O_c + a0 (x) V0
// ---------------------------------------------------------------------------
__global__ __launch_bounds__(256) void combine_kernel(
    const float* __restrict__ PartO, const float* __restrict__ PartP,
    const float* __restrict__ PartA0, const __bf16* __restrict__ Vt,
    __bf16* __restrict__ att) {
  const int b = blockIdx.x;            // 16 x 24
  const int nh = b / 24;
  const int rb = 8 + (b - nh * 24);
  const int nc = (rb < 16) ? 2 : ((rb < 24) ? 3 : 4);
  const int t0 = (rb < 16) ? 8 + ((rb - 8) << 1)
               : (rb < 24) ? 24 + (rb - 16) * 3
                           : 48 + ((rb - 24) << 2);
  const int n = nh >> 3, h = nh & 7;
  const int tid = threadIdx.x;
  const int r = tid >> 2, db = (tid & 3) << 4;

  float acc[16];
#pragma unroll
  for (int j = 0; j < 16; ++j) acc[j] = 0.f;
  float fac = 1.f;
  for (int c = 0; c < nc; ++c) {
    const int slot = nh * 72 + (t0 - 8) + c;
    const float* po = PartO + (size_t)slot * 4096 + r * 64 + db;
    const float P = PartP[slot * 64 + r];
#pragma unroll
    for (int q = 0; q < 4; ++q) {
      const float4 v = *(const float4*)(po + q * 4);
      acc[q * 4 + 0] += fac * v.x; acc[q * 4 + 1] += fac * v.y;
      acc[q * 4 + 2] += fac * v.z; acc[q * 4 + 3] += fac * v.w;
    }
    fac *= P;
  }
  const float a0 = PartA0[(nh * 24 + rb - 8) * 64 + r];
#pragma unroll
  for (int j = 0; j < 16; ++j)
    acc[j] += a0 * (float)Vt[(((size_t)(nh * 64 + db + j)) << 11)];

  __bf16 ob[16];
#pragma unroll
  for (int j = 0; j < 16; ++j) ob[j] = (__bf16)acc[j];
  __bf16* dst = att + ((size_t)(n * S_LEN + rb * 64 + r)) * DMODEL + h * HDIM + db;
  *(bf16x8*)dst       = *(bf16x8*)&ob[0];
  *(bf16x8*)(dst + 8) = *(bf16x8*)&ob[8];
}

// ---------------------------------------------------------------------------
// Kernel 4: out = att @ Wo^T + bo.  R10 wave decomposition: wave owns all
// 64 rows (4 A-frags) x units {wv, wv+4}: 16 MFMAs / 12 LDS reads per k-iter.
// ---------------------------------------------------------------------------
__global__ __launch_bounds__(256, 2) void out_gemm(const __bf16* __restrict__ Xa,
                                                   const __bf16* __restrict__ Wob,
                                                   const float* __restrict__ bo,
                                                   float* __restrict__ Out) {
  const int i0 = blockIdx.x << 6, j0 = blockIdx.y << 7;
  __shared__ __bf16 As[64][72];
  __shared__ __bf16 Bs[128][72];

  const int tid = threadIdx.x;
  const int wv = tid >> 6, lane = tid & 63;
  const int l = lane & 15, seg = lane >> 4;
  const int sr = tid >> 2, sc = (tid & 3) << 4;

  f32x4 O[2][4];                       // [j][r4]; unit u = wv + 4*j
#pragma unroll
  for (int j = 0; j < 2; ++j)
#pragma unroll
    for (int r4 = 0; r4 < 4; ++r4) O[j][r4] = (f32x4){0.f, 0.f, 0.f, 0.f};

  bf16x8 ar0, ar1, br[2][2];
#define LOADOUT(K0)                                                          \
  {                                                                          \
    const __bf16* xp = Xa + (size_t)(i0 + sr) * 512 + (K0) + sc;             \
    ar0 = *(const bf16x8*)xp; ar1 = *(const bf16x8*)(xp + 8);                \
    _Pragma("unroll")                                                        \
    for (int ps = 0; ps < 2; ++ps) {                                         \
      const __bf16* wp = Wob + (size_t)(j0 + ps * 64 + sr) * 512 + (K0) + sc;\
      br[ps][0] = *(const bf16x8*)wp; br[ps][1] = *(const bf16x8*)(wp + 8);  \
    }                                                                        \
  }

  LOADOUT(0)
  for (int k0 = 0; k0 < 512; k0 += 64) {
    __syncthreads();
    *(bf16x8*)&As[sr][sc]     = ar0;
    *(bf16x8*)&As[sr][sc + 8] = ar1;
#pragma unroll
    for (int ps = 0; ps < 2; ++ps) {
      *(bf16x8*)&Bs[ps * 64 + sr][sc]     = br[ps][0];
      *(bf16x8*)&Bs[ps * 64 + sr][sc + 8] = br[ps][1];
    }
    __syncthreads();
    if (k0 < 448) LOADOUT(k0 + 64)

    bf16x8 a0[4], a1[4];
#pragma unroll
    for (int r4 = 0; r4 < 4; ++r4) {
      a0[r4] = *(const bf16x8*)&As[r4 * 16 + l][seg * 8];
      a1[r4] = *(const bf16x8*)&As[r4 * 16 + l][seg * 8 + 32];
    }
#pragma unroll
    for (int j = 0; j < 2; ++j) {
      const int u = wv + 4 * j;
      bf16x8 b0 = *(const bf16x8*)&Bs[u * 16 + l][seg * 8];
      bf16x8 b1 = *(const bf16x8*)&Bs[u * 16 + l][seg * 8 + 32];
#pragma unroll
      for (int r4 = 0; r4 < 4; ++r4) {
        O[j][r4] = __builtin_amdgcn_mfma_f32_16x16x32_bf16(a0[r4], b0, O[j][r4], 0, 0, 0);
        O[j][r4] = __builtin_amdgcn_mfma_f32_16x16x32_bf16(a1[r4], b1, O[j][r4], 0, 0, 0);
      }
    }
  }

#pragma unroll
  for (int j = 0; j < 2; ++j) {
    const int u = wv + 4 * j;
    const float bb = bo[j0 + u * 16 + l];
#pragma unroll
    for (int r4 = 0; r4 < 4; ++r4)
#pragma unroll
      for (int reg = 0; reg < 4; ++reg) {
        const int m = r4 * 16 + (seg << 2) + reg;
        Out[(size_t)(i0 + m) * 512 + j0 + u * 16 + l] = O[j][r4][reg] + bb;
      }
  }
}

// ---------------------------------------------------------------------------
extern "C" void kernel_launch(void* const* d_in, const int* in_sizes, int n_in,
                              void* d_out, int out_size, void* d_ws, size_t ws_size,
                              hipStream_t stream) {
  (void)in_sizes; (void)n_in; (void)out_size; (void)ws_size;
  const float* seq  = (const float*)d_in[0];
  const float* mask = (const float*)d_in[1];
  const int*   pos  = (const int*)d_in[2];
  const float* Wq = (const float*)d_in[4];
  const float* bq = (const float*)d_in[5];
  const float* Wk = (const float*)d_in[6];
  const float* bk = (const float*)d_in[7];
  const float* Wv = (const float*)d_in[8];
  const float* bv = (const float*)d_in[9];
  const float* Wo = (const float*)d_in[10];
  const float* bo = (const float*)d_in[11];
  float* out = (float*)d_out;

  char* base = (char*)d_ws;
  __bf16* att = (__bf16*)base;                     // 4 MB  (4096 x 512 bf16)
  __bf16* Qh  = (__bf16*)(base + ( 4u << 20));     // 4 MB
  __bf16* Kh  = (__bf16*)(base + ( 8u << 20));     // 4 MB
  __bf16* Vt  = (__bf16*)(base + (12u << 20));     // 4 MB  [nh][d][2048]
  __bf16* Wb  = (__bf16*)(base + (16u << 20));     // 1.5 MB
  __bf16* Wob = (__bf16*)(base + (18u << 20));     // 0.5 MB
  __bf16* Xb  = (__bf16*)(base + (19u << 20));     // 4 MB  (dead after qkv)
  float* PartO  = (float*)(base + (23u << 20));    // 16*72*4096*4 = 18.9 MB
  float* PartP  = (float*)(base + (42u << 20));    // 16*72*64*4   = 295 KB
  float* PartA0 = (float*)(base + (43u << 20));    // 16*24*64*4   = 98 KB

  cvt_kernel<<<3072, 256, 0, stream>>>(seq, Wq, Wk, Wv, Wo, Xb, Wb, Wob);
  qkv_gemm<<<dim3(64, 8), 256, 0, stream>>>(Xb, Wb, bq, bk, bv, pos, Qh, Kh, Vt);
  attn_chunk<<<1280, 256, 0, stream>>>(Qh, Kh, Vt, mask, att, PartO, PartP, PartA0);
  combine_kernel<<<384, 256, 0, stream>>>(PartO, PartP, PartA0, Vt, att);
  out_gemm<<<dim3(64, 4), 256, 0, stream>>>(att, Wob, bo, out);
}